// Round 1
// baseline (220.545 us; speedup 1.0000x reference)
//
#include <hip/hip_runtime.h>
#include <hip/hip_bf16.h>

// Problem: B=64, ATT_SIZE(S)=1024, RNN_SIZE(D)=2048, ATT_HID(H)=512
// att_h = h @ W^T + b            [64, 512]
// dot   = tanh(p_att + att_h)    [64, 1024, 512]
// scores= dot @ w_alpha + b_a    [64, 1024]
// weight= softmax(scores, s)     [64, 1024]
// out   = weight @ att_feats     [64, 2048]

#define B 64
#define S 1024
#define D 2048
#define H 512

// ---------------- Kernel 1: att_h = h @ W^T + bias ----------------
// grid = H/4 = 128 blocks, 256 threads (4 waves). Block stages 4 W rows +
// one h row in LDS; wave w computes dot(h[b], W[j0+w]) for all b.
__global__ __launch_bounds__(256) void k_h2att(
    const float4* __restrict__ h4, const float4* __restrict__ W4,
    const float* __restrict__ bias, float* __restrict__ att_h) {
  __shared__ float4 lw[4][H];   // 4 rows x 2048 floats = 32 KB
  __shared__ float4 lh[H];      // 8 KB
  const int tid = threadIdx.x, lane = tid & 63, wave = tid >> 6;
  const int j0 = blockIdx.x * 4;
  for (int i = tid; i < 512; i += 256) {
    lw[0][i] = W4[(size_t)(j0 + 0) * 512 + i];
    lw[1][i] = W4[(size_t)(j0 + 1) * 512 + i];
    lw[2][i] = W4[(size_t)(j0 + 2) * 512 + i];
    lw[3][i] = W4[(size_t)(j0 + 3) * 512 + i];
  }
  for (int b = 0; b < B; ++b) {
    __syncthreads();  // protects lh from prev iter (and lw on first iter)
    for (int i = tid; i < 512; i += 256) lh[i] = h4[b * 512 + i];
    __syncthreads();
    float acc = 0.f;
#pragma unroll
    for (int i = lane; i < 512; i += 64) {
      float4 a = lh[i], w = lw[wave][i];
      acc += a.x * w.x + a.y * w.y + a.z * w.z + a.w * w.w;
    }
#pragma unroll
    for (int off = 32; off; off >>= 1) acc += __shfl_xor(acc, off, 64);
    if (lane == 0) att_h[b * H + j0 + wave] = acc + bias[j0 + wave];
  }
}

// ---------------- Kernel 2: scores = sum_h tanh(p + att_h) * w_alpha ----
// One wave per (b,s) row. grid = B*S/4 = 16384 blocks, 256 threads.
__global__ __launch_bounds__(256) void k_scores(
    const float4* __restrict__ p4, const float4* __restrict__ ah4,
    const float4* __restrict__ wa4, const float* __restrict__ b_alpha,
    float* __restrict__ scores) {
  const int tid = threadIdx.x, lane = tid & 63, wave = tid >> 6;
  const int row = blockIdx.x * 4 + wave;  // [0, B*S)
  const int b = row >> 10;
  const float4* p = p4 + (size_t)row * 128;   // 512 floats = 128 float4
  const float4* a = ah4 + (size_t)b * 128;
  float acc = 0.f;
#pragma unroll
  for (int i = 0; i < 2; ++i) {
    const int idx = lane + i * 64;
    float4 pv = p[idx], av = a[idx], wv = wa4[idx];
    acc += tanhf(pv.x + av.x) * wv.x;
    acc += tanhf(pv.y + av.y) * wv.y;
    acc += tanhf(pv.z + av.z) * wv.z;
    acc += tanhf(pv.w + av.w) * wv.w;
  }
#pragma unroll
  for (int off = 32; off; off >>= 1) acc += __shfl_xor(acc, off, 64);
  if (lane == 0) scores[row] = acc + b_alpha[0];
}

// ---------------- Kernel 3: softmax over s, in place -------------------
// grid = B = 64 blocks, 256 threads; each thread owns 4 scores.
__global__ __launch_bounds__(256) void k_softmax(float* __restrict__ sw) {
  const int b = blockIdx.x, tid = threadIdx.x, lane = tid & 63,
            wave = tid >> 6;
  __shared__ float red[4];
  float4* row = (float4*)(sw + (size_t)b * S);
  float4 v = row[tid];
  float m = fmaxf(fmaxf(v.x, v.y), fmaxf(v.z, v.w));
#pragma unroll
  for (int off = 32; off; off >>= 1) m = fmaxf(m, __shfl_xor(m, off, 64));
  if (lane == 0) red[wave] = m;
  __syncthreads();
  const float M = fmaxf(fmaxf(red[0], red[1]), fmaxf(red[2], red[3]));
  float e0 = expf(v.x - M), e1 = expf(v.y - M), e2 = expf(v.z - M),
        e3 = expf(v.w - M);
  float s = e0 + e1 + e2 + e3;
#pragma unroll
  for (int off = 32; off; off >>= 1) s += __shfl_xor(s, off, 64);
  __syncthreads();
  if (lane == 0) red[wave] = s;
  __syncthreads();
  const float inv = 1.f / (red[0] + red[1] + red[2] + red[3]);
  float4 o = {e0 * inv, e1 * inv, e2 * inv, e3 * inv};
  row[tid] = o;
}

// ---------------- Kernel 4: partial weighted sums over s ---------------
// blockIdx.x encodes (sc, b, dt): dt = bx&1 (d-tile of 1024), b=(bx>>1)&63,
// sc = bx>>7. 256 threads, one float4 of d per thread.
// partial layout: [nsc][64][2048] f32 (when nsc==1 this is exactly d_out).
__global__ __launch_bounds__(256) void k_wsum(
    const float4* __restrict__ f4, const float* __restrict__ weight,
    float4* __restrict__ partial, int s_per_chunk) {
  const int bx = blockIdx.x;
  const int dt = bx & 1, b = (bx >> 1) & 63, sc = bx >> 7;
  const int d4 = dt * 256 + threadIdx.x;  // float4 index within 512/row
  const float4* f = f4 + (size_t)b * S * 512 + d4;
  const float* wrow = weight + (size_t)b * S;
  float4 acc = {0.f, 0.f, 0.f, 0.f};
  const int s0 = sc * s_per_chunk;
#pragma unroll 8
  for (int s = s0; s < s0 + s_per_chunk; ++s) {
    const float w = wrow[s];
    float4 v = f[(size_t)s * 512];
    acc.x += w * v.x;
    acc.y += w * v.y;
    acc.z += w * v.z;
    acc.w += w * v.w;
  }
  partial[(size_t)sc * (B * 512) + b * 512 + d4] = acc;
}

// ---------------- Kernel 5: reduce partials into d_out -----------------
__global__ __launch_bounds__(256) void k_reduce(
    const float4* __restrict__ partial, float4* __restrict__ out, int nsc) {
  const int i = blockIdx.x * 256 + threadIdx.x;  // [0, B*D/4)
  float4 acc = {0.f, 0.f, 0.f, 0.f};
  for (int sc = 0; sc < nsc; ++sc) {
    float4 v = partial[(size_t)sc * (B * 512) + i];
    acc.x += v.x;
    acc.y += v.y;
    acc.z += v.z;
    acc.w += v.w;
  }
  out[i] = acc;
}

extern "C" void kernel_launch(void* const* d_in, const int* in_sizes, int n_in,
                              void* d_out, int out_size, void* d_ws,
                              size_t ws_size, hipStream_t stream) {
  const float* h = (const float*)d_in[0];
  const float* att_feats = (const float*)d_in[1];
  const float* p_att = (const float*)d_in[2];
  const float* W = (const float*)d_in[3];
  const float* bh = (const float*)d_in[4];
  const float* wa = (const float*)d_in[5];
  const float* ba = (const float*)d_in[6];
  float* out = (float*)d_out;
  float* ws = (float*)d_ws;

  float* att_h = ws;                    // 64*512   = 32768 floats
  float* scores = ws + 32768;           // 64*1024  = 65536 floats (softmax in place)
  float* partial = ws + 32768 + 65536;  // nsc*64*2048 floats

  int nsc = 8;
  const size_t need = (32768ull + 65536ull + (size_t)nsc * B * D) * 4ull;
  if (ws_size < need) nsc = 1;  // fallback: single chunk, write d_out directly

  k_h2att<<<H / 4, 256, 0, stream>>>((const float4*)h, (const float4*)W, bh,
                                     att_h);
  k_scores<<<B * S / 4, 256, 0, stream>>>((const float4*)p_att,
                                          (const float4*)att_h,
                                          (const float4*)wa, ba, scores);
  k_softmax<<<B, 256, 0, stream>>>(scores);
  if (nsc == 1) {
    k_wsum<<<128, 256, 0, stream>>>((const float4*)att_feats, scores,
                                    (float4*)out, S);
  } else {
    k_wsum<<<128 * nsc, 256, 0, stream>>>((const float4*)att_feats, scores,
                                          (float4*)partial, S / nsc);
    k_reduce<<<(B * D / 4) / 256, 256, 0, stream>>>((const float4*)partial,
                                                    (float4*)out, nsc);
  }
}

// Round 2
// 135.780 us; speedup vs baseline: 1.6243x; 1.6243x over previous
//
#include <hip/hip_runtime.h>
#include <hip/hip_bf16.h>

// Problem: B=64, ATT_SIZE(S)=1024, RNN_SIZE(D)=2048, ATT_HID(H)=512
// att_h = h @ W^T + b            [64, 512]
// dot   = tanh(p_att + att_h)    [64, 1024, 512]
// scores= dot @ w_alpha + b_a    [64, 1024]
// weight= softmax(scores, s)     [64, 1024]
// out   = weight @ att_feats     [64, 2048]

#define B 64
#define S 1024
#define D 2048
#define H 512

typedef float f32x4 __attribute__((ext_vector_type(4)));

__device__ __forceinline__ f32x4 nt_load4(const f32x4* p) {
  return __builtin_nontemporal_load(p);
}

// fast tanh: 1 - 2/(e^{2x}+1). Safe at +/-inf (e=inf -> 1; e=0 -> -1).
__device__ __forceinline__ float fast_tanh(float x) {
  float e = __expf(2.f * x);
  return 1.f - 2.f * __builtin_amdgcn_rcpf(e + 1.f);
}

// ---------------- Kernel 1: att_h = h @ W^T + bias ----------------
// One wave per (b,j) output. grid = B*H/4 = 8192 blocks x 256 threads.
// W is streamed once (4 MB); h rows are L1/L2-resident (512 KB total).
__global__ __launch_bounds__(256) void k_h2att(
    const f32x4* __restrict__ h4, const f32x4* __restrict__ W4,
    const float* __restrict__ bias, float* __restrict__ att_h) {
  const int tid = threadIdx.x, lane = tid & 63, wave = tid >> 6;
  const int row = blockIdx.x * 4 + wave;  // [0, B*H)
  const int b = row >> 9, j = row & (H - 1);
  const f32x4* w = W4 + (size_t)j * 512;  // 2048 floats = 512 f32x4
  const f32x4* a = h4 + (size_t)b * 512;
  float acc = 0.f;
#pragma unroll
  for (int i = 0; i < 8; ++i) {
    const int idx = lane + i * 64;
    f32x4 wv = w[idx], av = a[idx];
    acc += wv.x * av.x + wv.y * av.y + wv.z * av.z + wv.w * av.w;
  }
#pragma unroll
  for (int off = 32; off; off >>= 1) acc += __shfl_xor(acc, off, 64);
  if (lane == 0) att_h[row] = acc + bias[j];
}

// ---------------- Kernel 2: scores = sum_h tanh(p + att_h) * w_alpha ----
// One wave per (b,s) row. grid = B*S/4 = 16384 blocks, 256 threads.
__global__ __launch_bounds__(256) void k_scores(
    const f32x4* __restrict__ p4, const f32x4* __restrict__ ah4,
    const f32x4* __restrict__ wa4, const float* __restrict__ b_alpha,
    float* __restrict__ scores) {
  const int tid = threadIdx.x, lane = tid & 63, wave = tid >> 6;
  const int row = blockIdx.x * 4 + wave;  // [0, B*S)
  const int b = row >> 10;
  const f32x4* p = p4 + (size_t)row * 128;  // 512 floats = 128 f32x4
  const f32x4* a = ah4 + (size_t)b * 128;
  float acc = 0.f;
#pragma unroll
  for (int i = 0; i < 2; ++i) {
    const int idx = lane + i * 64;
    f32x4 pv = nt_load4(p + idx);
    f32x4 av = a[idx], wv = wa4[idx];
    acc += fast_tanh(pv.x + av.x) * wv.x;
    acc += fast_tanh(pv.y + av.y) * wv.y;
    acc += fast_tanh(pv.z + av.z) * wv.z;
    acc += fast_tanh(pv.w + av.w) * wv.w;
  }
#pragma unroll
  for (int off = 32; off; off >>= 1) acc += __shfl_xor(acc, off, 64);
  if (lane == 0) scores[row] = acc + b_alpha[0];
}

// ---------------- Kernel 3: softmax over s, in place -------------------
// grid = B = 64 blocks, 256 threads; each thread owns 4 scores.
__global__ __launch_bounds__(256) void k_softmax(float* __restrict__ sw) {
  const int b = blockIdx.x, tid = threadIdx.x, lane = tid & 63,
            wave = tid >> 6;
  __shared__ float red[4];
  f32x4* row = (f32x4*)(sw + (size_t)b * S);
  f32x4 v = row[tid];
  float m = fmaxf(fmaxf(v.x, v.y), fmaxf(v.z, v.w));
#pragma unroll
  for (int off = 32; off; off >>= 1) m = fmaxf(m, __shfl_xor(m, off, 64));
  if (lane == 0) red[wave] = m;
  __syncthreads();
  const float M = fmaxf(fmaxf(red[0], red[1]), fmaxf(red[2], red[3]));
  float e0 = __expf(v.x - M), e1 = __expf(v.y - M), e2 = __expf(v.z - M),
        e3 = __expf(v.w - M);
  float s = e0 + e1 + e2 + e3;
#pragma unroll
  for (int off = 32; off; off >>= 1) s += __shfl_xor(s, off, 64);
  __syncthreads();
  if (lane == 0) red[wave] = s;
  __syncthreads();
  const float inv = 1.f / (red[0] + red[1] + red[2] + red[3]);
  f32x4 o = {e0 * inv, e1 * inv, e2 * inv, e3 * inv};
  row[tid] = o;
}

// ---------------- Kernel 4: partial weighted sums over s ---------------
// blockIdx.x encodes (sc, b, dt): dt = bx&1 (d-tile of 1024), b=(bx>>1)&63,
// sc = bx>>7. 256 threads, one f32x4 of d per thread.
// partial layout: [nsc][64][2048] f32 (when nsc==1 this is exactly d_out).
__global__ __launch_bounds__(256) void k_wsum(
    const f32x4* __restrict__ f4, const float* __restrict__ weight,
    f32x4* __restrict__ partial, int s_per_chunk) {
  const int bx = blockIdx.x;
  const int dt = bx & 1, b = (bx >> 1) & 63, sc = bx >> 7;
  const int d4 = dt * 256 + threadIdx.x;  // f32x4 index within 512/row
  const f32x4* f = f4 + (size_t)b * S * 512 + d4;
  const float* wrow = weight + (size_t)b * S;
  f32x4 acc = {0.f, 0.f, 0.f, 0.f};
  const int s0 = sc * s_per_chunk;
#pragma unroll 8
  for (int s = s0; s < s0 + s_per_chunk; ++s) {
    const float w = wrow[s];
    f32x4 v = nt_load4(f + (size_t)s * 512);
    acc.x += w * v.x;
    acc.y += w * v.y;
    acc.z += w * v.z;
    acc.w += w * v.w;
  }
  partial[(size_t)sc * (B * 512) + b * 512 + d4] = acc;
}

// ---------------- Kernel 5: reduce partials into d_out -----------------
__global__ __launch_bounds__(256) void k_reduce(
    const f32x4* __restrict__ partial, f32x4* __restrict__ out, int nsc) {
  const int i = blockIdx.x * 256 + threadIdx.x;  // [0, B*D/4)
  f32x4 acc = {0.f, 0.f, 0.f, 0.f};
  for (int sc = 0; sc < nsc; ++sc) {
    f32x4 v = partial[(size_t)sc * (B * 512) + i];
    acc.x += v.x;
    acc.y += v.y;
    acc.z += v.z;
    acc.w += v.w;
  }
  out[i] = acc;
}

extern "C" void kernel_launch(void* const* d_in, const int* in_sizes, int n_in,
                              void* d_out, int out_size, void* d_ws,
                              size_t ws_size, hipStream_t stream) {
  const float* h = (const float*)d_in[0];
  const float* att_feats = (const float*)d_in[1];
  const float* p_att = (const float*)d_in[2];
  const float* W = (const float*)d_in[3];
  const float* bh = (const float*)d_in[4];
  const float* wa = (const float*)d_in[5];
  const float* ba = (const float*)d_in[6];
  float* out = (float*)d_out;
  float* ws = (float*)d_ws;

  float* att_h = ws;                    // 64*512   = 32768 floats
  float* scores = ws + 32768;           // 64*1024  = 65536 floats (softmax in place)
  float* partial = ws + 32768 + 65536;  // nsc*64*2048 floats

  int nsc = 16;
  const size_t need = (32768ull + 65536ull + (size_t)nsc * B * D) * 4ull;
  if (ws_size < need) nsc = 1;  // fallback: single chunk, write d_out directly

  k_h2att<<<B * H / 4, 256, 0, stream>>>((const f32x4*)h, (const f32x4*)W, bh,
                                         att_h);
  k_scores<<<B * S / 4, 256, 0, stream>>>((const f32x4*)p_att,
                                          (const f32x4*)att_h,
                                          (const f32x4*)wa, ba, scores);
  k_softmax<<<B, 256, 0, stream>>>(scores);
  if (nsc == 1) {
    k_wsum<<<128, 256, 0, stream>>>((const f32x4*)att_feats, scores,
                                    (f32x4*)out, S);
  } else {
    k_wsum<<<128 * nsc, 256, 0, stream>>>((const f32x4*)att_feats, scores,
                                          (f32x4*)partial, S / nsc);
    k_reduce<<<(B * D / 4) / 256, 256, 0, stream>>>((const f32x4*)partial,
                                                    (f32x4*)out, nsc);
  }
}

// Round 3
// 135.097 us; speedup vs baseline: 1.6325x; 1.0051x over previous
//
#include <hip/hip_runtime.h>
#include <hip/hip_bf16.h>

// Problem: B=64, ATT_SIZE(S)=1024, RNN_SIZE(D)=2048, ATT_HID(H)=512
// att_h = h @ W^T + b            [64, 512]
// dot   = tanh(p_att + att_h)    [64, 1024, 512]
// scores= dot @ w_alpha + b_a    [64, 1024]
// weight= softmax(scores, s)     [64, 1024]
// out   = weight @ att_feats     [64, 2048]

#define B 64
#define S 1024
#define D 2048
#define H 512

typedef float f32x4 __attribute__((ext_vector_type(4)));

__device__ __forceinline__ f32x4 nt_load4(const f32x4* p) {
  return __builtin_nontemporal_load(p);
}

// fast tanh: 1 - 2/(e^{2x}+1). Safe at +/-inf (e=inf -> 1; e=0 -> -1).
__device__ __forceinline__ float fast_tanh(float x) {
  float e = __expf(2.f * x);
  return 1.f - 2.f * __builtin_amdgcn_rcpf(e + 1.f);
}

// ---------------- Kernel 1: att_h = h @ W^T + bias ----------------
// Each WAVE computes a 4b x 4j tile (16 outputs): reads 4 h-rows + 4 W-rows
// (64 KB) per 16 outputs instead of 16 KB per single output -> 4x less L2
// traffic than wave-per-output. tiles = (B/4)*(H/4) = 2048; 512 blocks.
__global__ __launch_bounds__(256) void k_h2att(
    const f32x4* __restrict__ h4, const f32x4* __restrict__ W4,
    const float* __restrict__ bias, float* __restrict__ att_h) {
  const int tid = threadIdx.x, lane = tid & 63, wave = tid >> 6;
  const int tile = blockIdx.x * 4 + wave;  // [0, 2048)
  const int b0 = (tile >> 7) << 2;         // [0, 64) step 4
  const int j0 = (tile & 127) << 2;        // [0, 512) step 4
  float acc[4][4] = {};
#pragma unroll
  for (int i = 0; i < 8; ++i) {
    const int idx = lane + i * 64;  // [0, 512) f32x4 within a 2048-f row
    f32x4 hv[4], wv[4];
#pragma unroll
    for (int x = 0; x < 4; ++x) hv[x] = h4[(size_t)(b0 + x) * 512 + idx];
#pragma unroll
    for (int x = 0; x < 4; ++x) wv[x] = W4[(size_t)(j0 + x) * 512 + idx];
#pragma unroll
    for (int bb = 0; bb < 4; ++bb)
#pragma unroll
      for (int jj = 0; jj < 4; ++jj)
        acc[bb][jj] += hv[bb].x * wv[jj].x + hv[bb].y * wv[jj].y +
                       hv[bb].z * wv[jj].z + hv[bb].w * wv[jj].w;
  }
#pragma unroll
  for (int bb = 0; bb < 4; ++bb)
#pragma unroll
    for (int jj = 0; jj < 4; ++jj) {
      float a = acc[bb][jj];
#pragma unroll
      for (int off = 32; off; off >>= 1) a += __shfl_xor(a, off, 64);
      if (lane == bb * 4 + jj)  // spread the 16 stores over 16 lanes
        att_h[(b0 + bb) * H + j0 + jj] = a + bias[j0 + jj];
    }
}

// ---------------- Kernel 2: scores = sum_h tanh(p + att_h) * w_alpha ----
// One wave per (b,s) row. grid = B*S/4 = 16384 blocks, 256 threads.
__global__ __launch_bounds__(256) void k_scores(
    const f32x4* __restrict__ p4, const f32x4* __restrict__ ah4,
    const f32x4* __restrict__ wa4, const float* __restrict__ b_alpha,
    float* __restrict__ scores) {
  const int tid = threadIdx.x, lane = tid & 63, wave = tid >> 6;
  const int row = blockIdx.x * 4 + wave;  // [0, B*S)
  const int b = row >> 10;
  const f32x4* p = p4 + (size_t)row * 128;  // 512 floats = 128 f32x4
  const f32x4* a = ah4 + (size_t)b * 128;
  float acc = 0.f;
#pragma unroll
  for (int i = 0; i < 2; ++i) {
    const int idx = lane + i * 64;
    f32x4 pv = nt_load4(p + idx);
    f32x4 av = a[idx], wv = wa4[idx];
    acc += fast_tanh(pv.x + av.x) * wv.x;
    acc += fast_tanh(pv.y + av.y) * wv.y;
    acc += fast_tanh(pv.z + av.z) * wv.z;
    acc += fast_tanh(pv.w + av.w) * wv.w;
  }
#pragma unroll
  for (int off = 32; off; off >>= 1) acc += __shfl_xor(acc, off, 64);
  if (lane == 0) scores[row] = acc + b_alpha[0];
}

// ---------------- Kernel 3: fused softmax + partial weighted sums -------
// blockIdx.x encodes (sc, b, dt): dt = bx&1 (d-tile of 1024), b=(bx>>1)&63,
// sc = bx>>7. Each block first redundantly computes softmax(scores[b,:])
// into LDS (scores row is L2-resident, shared by 2*nsc blocks), then
// accumulates its s-chunk. partial layout: [nsc][64][2048] f32.
__global__ __launch_bounds__(256) void k_wsum(
    const f32x4* __restrict__ f4, const float* __restrict__ scores,
    f32x4* __restrict__ partial, int s_per_chunk) {
  __shared__ float wlds[S];
  __shared__ float redm[4], reds[4];
  const int tid = threadIdx.x, lane = tid & 63, wave = tid >> 6;
  const int bx = blockIdx.x;
  const int dt = bx & 1, b = (bx >> 1) & 63, sc = bx >> 7;

  // ---- softmax(scores[b,:]) -> wlds[0..S) ----
  f32x4 v = ((const f32x4*)(scores + (size_t)b * S))[tid];
  float m = fmaxf(fmaxf(v.x, v.y), fmaxf(v.z, v.w));
#pragma unroll
  for (int off = 32; off; off >>= 1) m = fmaxf(m, __shfl_xor(m, off, 64));
  if (lane == 0) redm[wave] = m;
  __syncthreads();
  const float M = fmaxf(fmaxf(redm[0], redm[1]), fmaxf(redm[2], redm[3]));
  float e0 = __expf(v.x - M), e1 = __expf(v.y - M), e2 = __expf(v.z - M),
        e3 = __expf(v.w - M);
  float ss = e0 + e1 + e2 + e3;
#pragma unroll
  for (int off = 32; off; off >>= 1) ss += __shfl_xor(ss, off, 64);
  if (lane == 0) reds[wave] = ss;
  __syncthreads();
  const float inv = 1.f / (reds[0] + reds[1] + reds[2] + reds[3]);
  f32x4 wv = {e0 * inv, e1 * inv, e2 * inv, e3 * inv};
  ((f32x4*)wlds)[tid] = wv;
  __syncthreads();

  // ---- weighted partial sum over this block's s-chunk ----
  const int d4 = dt * 256 + tid;  // f32x4 index within 512/row
  const f32x4* f = f4 + (size_t)b * S * 512 + d4;
  f32x4 acc = {0.f, 0.f, 0.f, 0.f};
  const int s0 = sc * s_per_chunk;
#pragma unroll 8
  for (int s = s0; s < s0 + s_per_chunk; ++s) {
    const float w = wlds[s];
    f32x4 vv = nt_load4(f + (size_t)s * 512);
    acc.x += w * vv.x;
    acc.y += w * vv.y;
    acc.z += w * vv.z;
    acc.w += w * vv.w;
  }
  partial[(size_t)sc * (B * 512) + b * 512 + d4] = acc;
}

// ---------------- Kernel 4: reduce partials into d_out -----------------
__global__ __launch_bounds__(256) void k_reduce(
    const f32x4* __restrict__ partial, f32x4* __restrict__ out, int nsc) {
  const int i = blockIdx.x * 256 + threadIdx.x;  // [0, B*D/4)
  f32x4 acc = {0.f, 0.f, 0.f, 0.f};
  for (int sc = 0; sc < nsc; ++sc) {
    f32x4 v = partial[(size_t)sc * (B * 512) + i];
    acc.x += v.x;
    acc.y += v.y;
    acc.z += v.z;
    acc.w += v.w;
  }
  out[i] = acc;
}

extern "C" void kernel_launch(void* const* d_in, const int* in_sizes, int n_in,
                              void* d_out, int out_size, void* d_ws,
                              size_t ws_size, hipStream_t stream) {
  const float* h = (const float*)d_in[0];
  const float* att_feats = (const float*)d_in[1];
  const float* p_att = (const float*)d_in[2];
  const float* W = (const float*)d_in[3];
  const float* bh = (const float*)d_in[4];
  const float* wa = (const float*)d_in[5];
  const float* ba = (const float*)d_in[6];
  float* out = (float*)d_out;
  float* ws = (float*)d_ws;

  float* att_h = ws;                    // 64*512   = 32768 floats
  float* scores = ws + 32768;           // 64*1024  = 65536 floats
  float* partial = ws + 32768 + 65536;  // nsc*64*2048 floats

  int nsc = 16;
  const size_t need = (32768ull + 65536ull + (size_t)nsc * B * D) * 4ull;
  if (ws_size < need) nsc = 1;  // fallback: single chunk, write d_out directly

  k_h2att<<<(B / 4) * (H / 4) / 4, 256, 0, stream>>>(
      (const f32x4*)h, (const f32x4*)W, bh, att_h);
  k_scores<<<B * S / 4, 256, 0, stream>>>((const f32x4*)p_att,
                                          (const f32x4*)att_h,
                                          (const f32x4*)wa, ba, scores);
  if (nsc == 1) {
    k_wsum<<<128, 256, 0, stream>>>((const f32x4*)att_feats, scores,
                                    (f32x4*)out, S);
  } else {
    k_wsum<<<128 * nsc, 256, 0, stream>>>((const f32x4*)att_feats, scores,
                                          (f32x4*)partial, S / nsc);
    k_reduce<<<(B * D / 4) / 256, 256, 0, stream>>>((const f32x4*)partial,
                                                    (f32x4*)out, nsc);
  }
}